// Round 18
// baseline (437.696 us; speedup 1.0000x reference)
//
#include <hip/hip_runtime.h>

// WKV7 (RWKV-7) forward scan. T=2048, H=64, D=64.
// R18 = R14 structure with 8 cols/lane (f32x8). Model (R5-R17): step time ~
// max(shared per-CU mem-pipe wall ~= 12cyc x (DS+VMEM wave-ops/CU/step),
// per-wave chain). R14 = 33 ops -> 360cyc. C=8 halves blocks/head:
//  - 512 blocks x 64 thr (2 waves/CU): per-CU ops 28 (22 DS + 4 vmem + 2 st)
//  - FETCH halves (8 blocks/head read each head's vectors)
//  - row = 8 lanes -> 3-level DPP reduce (xor1, xor2, half_mirror): carried
//    chain -2 levels (~-50 cyc)
// Machinery from R14 verbatim: width-16 2-op global_load_lds staging, 8-slot
// 2KB ring, 3-deep reg buffers, duo-interleaved reduce (s_nop 1 entry),
// y-store pipelined one body, counted vmcnt/lgkmcnt.

typedef float f32x4 __attribute__((ext_vector_type(4)));

constexpr int T_LEN = 2048;
constexpr int DD    = 64;
constexpr int HD    = 64 * 64;   // 4096

#define AS1 __attribute__((address_space(1)))
#define AS3 __attribute__((address_space(3)))

struct Buf { f32x4 r0, r1, e0, e1, k0, k1, a0, a1, b0, b1; float vv; };

__global__ __launch_bounds__(256)
void exp_kernel(const float4* __restrict__ w, float4* __restrict__ ew, int n4) {
  int i = blockIdx.x * blockDim.x + threadIdx.x;
  int stride = gridDim.x * blockDim.x;
  for (; i < n4; i += stride) {
    float4 x = w[i];
    float4 o;
    o.x = __expf(x.x); o.y = __expf(x.y); o.z = __expf(x.z); o.w = __expf(x.w);
    ew[i] = o;
  }
}

template<int CTRL>
__device__ __forceinline__ float dpp_add(float x) {
  int y = __builtin_amdgcn_update_dpp(0, __float_as_int(x), CTRL, 0xf, 0xf, true);
  return x + __int_as_float(y);
}

// Serial 8-lane reduce (prologue only): lanes grouped 8-consecutive.
__device__ __forceinline__ float row8_reduce(float x) {
  x = dpp_add<0xB1>(x);    // quad_perm [1,0,3,2] : xor1
  x = dpp_add<0x4E>(x);    // quad_perm [2,3,0,1] : xor2
  x = dpp_add<0x141>(x);   // row_half_mirror    : other quad of the 8-group
  return x;
}

// Two interleaved 8-lane reductions (3 levels each). s_nop 1 covers the
// entry VALU-write -> DPP-read hazard (R8 lesson); interior spacing >=2.
__device__ __forceinline__ void duo_reduce8(float& a, float& b) {
  float t0, t1;
  asm volatile(
    "s_nop 1\n\t"
    "v_mov_b32_dpp %2, %0 quad_perm:[1,0,3,2] row_mask:0xf bank_mask:0xf\n\t"
    "v_mov_b32_dpp %3, %1 quad_perm:[1,0,3,2] row_mask:0xf bank_mask:0xf\n\t"
    "s_nop 0\n\t"
    "v_add_f32 %0, %0, %2\n\t"
    "v_add_f32 %1, %1, %3\n\t"
    "s_nop 0\n\t"
    "v_mov_b32_dpp %2, %0 quad_perm:[2,3,0,1] row_mask:0xf bank_mask:0xf\n\t"
    "v_mov_b32_dpp %3, %1 quad_perm:[2,3,0,1] row_mask:0xf bank_mask:0xf\n\t"
    "s_nop 0\n\t"
    "v_add_f32 %0, %0, %2\n\t"
    "v_add_f32 %1, %1, %3\n\t"
    "s_nop 0\n\t"
    "v_mov_b32_dpp %2, %0 row_half_mirror row_mask:0xf bank_mask:0xf\n\t"
    "v_mov_b32_dpp %3, %1 row_half_mirror row_mask:0xf bank_mask:0xf\n\t"
    "s_nop 0\n\t"
    "v_add_f32 %0, %0, %2\n\t"
    "v_add_f32 %1, %1, %3"
    : "+v"(a), "+v"(b), "=&v"(t0), "=&v"(t1));
}

__device__ __forceinline__ float dot4(const f32x4& x, const f32x4& y) {
  return fmaf(x[3], y[3], fmaf(x[2], y[2], fmaf(x[1], y[1], x[0] * y[0])));
}

__device__ __forceinline__ void gload_lds16(const float* g, const float* l) {
  __builtin_amdgcn_global_load_lds((const AS1 unsigned*)g, (AS3 unsigned*)l, 16, 0, 0);
}

__global__ __launch_bounds__(64, 1)
void wkv7_scan(const float* __restrict__ R, const float* __restrict__ EW,
               const float* __restrict__ K, const float* __restrict__ V,
               const float* __restrict__ A, const float* __restrict__ B,
               const float* __restrict__ S0, float* __restrict__ X,
               float* __restrict__ SOUT)
{
  // 8 slots x 512 floats (2KB: R|EW|K|A | B|V|pad) = 16 KB
  __shared__ float smem[4096];

  const int blk = blockIdx.x;          // 0..511
  const int xcd = blk & 7;
  const int m   = blk >> 3;            // 0..63
  const int h   = xcd * 8 + (m & 7);   // head 0..63 (8 blocks/head, same XCD)
  const int br  = m >> 3;              // row block 0..7

  const int lane = threadIdx.x;        // 0..63
  const int cg   = lane & 7;           // col group -> cols [cg*8, cg*8+8)
  const int rl   = lane >> 3;          // local row 0..7
  const int row  = br * 8 + rl;        // 0..63
  const int c0   = cg * 8;

  // Staging sources (width-16 lane grouping, R14 verbatim):
  const int g1    = lane >> 4;         // source-array group 0..3
  const int sub16 = lane & 15;         // 16B chunk within the 256B array
  const float* base1 = (g1 == 0) ? R : (g1 == 1) ? EW : (g1 == 2) ? K : A;
  const float* base2 = (g1 == 0) ? B : V;   // g1>=1 dups V into pad
  const float* p1 = base1 + h * DD + sub16 * 4;
  const float* p2 = base2 + h * DD + sub16 * 4;

  const unsigned lb  = (unsigned)(uintptr_t)(AS3 float*)&smem[0];
  const unsigned vab = lb + (unsigned)(cg * 32);   // vector-read base (8 fl)
  const unsigned vvb = lb + (unsigned)(row * 4);   // v-read base (+1280 imm)

  const int voffb = (h * DD + row) * 4;   // byte offset of (h,row) in one step

  f32x4 s0, s1;
  {
    const f32x4* sp = (const f32x4*)(S0 + (size_t)h * DD * DD + row * DD + c0);
    s0 = sp[0]; s1 = sp[1];
  }

  auto stage = [&](int tt, int slot) {
    const size_t o = (size_t)tt * HD;
    const float* l = &smem[slot * 512];
    gload_lds16(p1 + o, l);          // R|EW|K|A -> slot[0..1024)B
    gload_lds16(p2 + o, l + 256);    // B|V|pad  -> slot[1024..2048)B
  };

  auto lds_read = [&](Buf& d, int slot) {
    unsigned va = vab + (unsigned)(slot * 2048);
    unsigned vv = vvb + (unsigned)(slot * 2048);
    asm volatile(
      "ds_read_b128 %0, %11\n\t"
      "ds_read_b128 %1, %11 offset:16\n\t"
      "ds_read_b128 %2, %11 offset:256\n\t"
      "ds_read_b128 %3, %11 offset:272\n\t"
      "ds_read_b128 %4, %11 offset:512\n\t"
      "ds_read_b128 %5, %11 offset:528\n\t"
      "ds_read_b128 %6, %11 offset:768\n\t"
      "ds_read_b128 %7, %11 offset:784\n\t"
      "ds_read_b128 %8, %11 offset:1024\n\t"
      "ds_read_b128 %9, %11 offset:1040\n\t"
      "ds_read_b32  %10, %12 offset:1280"
      : "=&v"(d.r0), "=&v"(d.r1), "=&v"(d.e0), "=&v"(d.e1),
        "=&v"(d.k0), "=&v"(d.k1), "=&v"(d.a0), "=&v"(d.a1),
        "=&v"(d.b0), "=&v"(d.b1), "=&v"(d.vv)
      : "v"(va), "v"(vv) : "memory");
  };

  // Wait for nx1's 11 ds_reads (issued last body; only the 11 just issued
  // for nx2 are newer). Tied to nx1's regs as a data dependency.
  auto wait_nx1 = [&](Buf& d) {
    asm volatile("s_waitcnt lgkmcnt(11)"
                 : "+v"(d.r0), "+v"(d.r1), "+v"(d.e0), "+v"(d.e1),
                   "+v"(d.k0), "+v"(d.k1), "+v"(d.a0), "+v"(d.a1),
                   "+v"(d.b0), "+v"(d.b1), "+v"(d.vv));
  };

  float sa;                 // sa_t = S_{t-1}.a_t, ready at body t entry
  float yprev = 0.0f;       // y_{t-1}, stored at body t
  int   yoff_prev = 2047 * (HD * 4) + voffb;  // body-0 dummy target
                                              // (epilogue overwrites)

  auto body = [&](Buf& cur, Buf& nx1, Buf& nx2, int t) {
    // stage(t+2) (issued at body t-6) resident: bodies t-5..t-1 issued
    // 5 x (2 loads + 1 store) = 15 newer vmem ops -> vmcnt(15).
    asm volatile("s_waitcnt vmcnt(15)" ::: "memory");
    lds_read(nx2, (t + 2) & 7);
    wait_nx1(nx1);

    // ---- state update for step t (sa ready since last body) ----
    const float vv = cur.vv;
    s0[0] = fmaf(cur.e0[0], s0[0], fmaf(sa, cur.b0[0], vv * cur.k0[0]));
    s0[1] = fmaf(cur.e0[1], s0[1], fmaf(sa, cur.b0[1], vv * cur.k0[1]));
    s0[2] = fmaf(cur.e0[2], s0[2], fmaf(sa, cur.b0[2], vv * cur.k0[2]));
    s0[3] = fmaf(cur.e0[3], s0[3], fmaf(sa, cur.b0[3], vv * cur.k0[3]));
    s1[0] = fmaf(cur.e1[0], s1[0], fmaf(sa, cur.b1[0], vv * cur.k1[0]));
    s1[1] = fmaf(cur.e1[1], s1[1], fmaf(sa, cur.b1[1], vv * cur.k1[1]));
    s1[2] = fmaf(cur.e1[2], s1[2], fmaf(sa, cur.b1[2], vv * cur.k1[2]));
    s1[3] = fmaf(cur.e1[3], s1[3], fmaf(sa, cur.b1[3], vv * cur.k1[3]));

    // ---- both dots (partials over this lane's 8 cols) ----
    float qd = dot4(s0, nx1.a0) + dot4(s1, nx1.a1);   // -> sa_{t+1}
    float yd = dot4(s0, cur.r0) + dot4(s1, cur.r1);   // -> y_t

    // ---- store y_{t-1} while reductions run ----
    if (cg == 0) {   // 8 lanes, 8 contiguous rows: 32B coalesced
      asm volatile("global_store_dword %0, %1, %2"
                   :: "v"(yoff_prev), "v"(yprev), "s"(X) : "memory");
    }
    stage((t + 8) & (T_LEN - 1), t & 7);

    // ---- interleaved dual 8-lane reduction (3 levels) ----
    duo_reduce8(qd, yd);
    sa    = qd;
    yprev = yd;
    yoff_prev = t * (HD * 4) + voffb;
  };

  // Prologue: fill ring (issue order = count order).
  for (int i = 0; i < 8; ++i) {
    stage(i, i);
    __builtin_amdgcn_sched_barrier(0);
  }
  // Slots 0,1 done: stages 2..7 = 12 newer load ops.
  asm volatile("s_waitcnt vmcnt(12)" ::: "memory");

  Buf B0, B1, B2, B3;
  lds_read(B0, 0);
  lds_read(B1, 1);
  asm volatile("s_waitcnt lgkmcnt(0)"
               : "+v"(B0.r0), "+v"(B0.e0), "+v"(B0.k0), "+v"(B0.a0),
                 "+v"(B0.b0), "+v"(B0.a1), "+v"(B0.vv), "+v"(B1.a0),
                 "+v"(B1.a1));

  // sa_0 = S_init . a_0 (prologue pays one serial 8-lane reduce)
  sa = row8_reduce(dot4(s0, B0.a0) + dot4(s1, B0.a1));

  for (int t = 0; t < T_LEN; t += 4) {
    body(B0, B1, B2, t);
    body(B1, B2, B3, t + 1);
    body(B2, B3, B0, t + 2);
    body(B3, B0, B1, t + 3);
  }

  // Epilogue: final y (t=2047) — overwrites body-0's dummy store.
  if (cg == 0) {
    asm volatile("global_store_dword %0, %1, %2"
                 :: "v"(yoff_prev), "v"(yprev), "s"(X) : "memory");
  }

  f32x4* so = (f32x4*)(SOUT + (size_t)h * DD * DD + row * DD + c0);
  so[0] = s0; so[1] = s1;
}

extern "C" void kernel_launch(void* const* d_in, const int* in_sizes, int n_in,
                              void* d_out, int out_size, void* d_ws, size_t ws_size,
                              hipStream_t stream) {
  // setup_inputs order: seq_length, r, w, k, v, a, b, state2
  const float* r  = (const float*)d_in[1];
  const float* w  = (const float*)d_in[2];
  const float* k  = (const float*)d_in[3];
  const float* v  = (const float*)d_in[4];
  const float* a  = (const float*)d_in[5];
  const float* b  = (const float*)d_in[6];
  const float* s0 = (const float*)d_in[7];

  float* x    = (float*)d_out;                     // (T, H, 1, D)
  float* sout = x + (size_t)T_LEN * HD;            // (H, D, D)

  float* ew = (float*)d_ws;
  (void)ws_size; (void)in_sizes; (void)n_in;

  int n4 = T_LEN * HD / 4;
  hipLaunchKernelGGL(exp_kernel, dim3(1024), dim3(256), 0, stream,
                     (const float4*)w, (float4*)ew, n4);
  hipLaunchKernelGGL(wkv7_scan, dim3(512), dim3(64), 0, stream,
                     r, ew, k, v, a, b, s0, x, sout);
}

// Round 19
// 242.915 us; speedup vs baseline: 1.8018x; 1.8018x over previous
//
#include <hip/hip_runtime.h>

// WKV7 (RWKV-7) forward scan. T=2048, H=64, D=64.
// R19 = R14 verbatim + batched y-store (the ONE isolated op-count lever left).
// Model (fitted R5-R18): step time ~ max(per-CU mem-pipe wall ~= 12 cyc x
// (DS+VMEM wave-ops/CU/step), per-wave dependent chain). R14 = 33 ops ~360cyc,
// balanced. Batching y (lane cg<8 holds step t0+cg, one scatter store per 8
// steps) cuts ops to 32.5 with zero chain/issue cost elsewhere.
// Everything else identical to R14 (best verified: 307us scan / 291us bench).

typedef float f32x4 __attribute__((ext_vector_type(4)));

constexpr int T_LEN = 2048;
constexpr int DD    = 64;
constexpr int HD    = 64 * 64;   // 4096

#define AS1 __attribute__((address_space(1)))
#define AS3 __attribute__((address_space(3)))

struct Buf { f32x4 r, e, k, a, b; float vv; };

__global__ __launch_bounds__(256)
void exp_kernel(const float4* __restrict__ w, float4* __restrict__ ew, int n4) {
  int i = blockIdx.x * blockDim.x + threadIdx.x;
  int stride = gridDim.x * blockDim.x;
  for (; i < n4; i += stride) {
    float4 x = w[i];
    float4 o;
    o.x = __expf(x.x); o.y = __expf(x.y); o.z = __expf(x.z); o.w = __expf(x.w);
    ew[i] = o;
  }
}

template<int CTRL>
__device__ __forceinline__ float dpp_add(float x) {
  int y = __builtin_amdgcn_update_dpp(0, __float_as_int(x), CTRL, 0xf, 0xf, true);
  return x + __int_as_float(y);
}

// Serial 16-lane reduce (prologue only).
__device__ __forceinline__ float row16_reduce(float x) {
  x = dpp_add<0xB1>(x);    // quad_perm [1,0,3,2]
  x = dpp_add<0x4E>(x);    // quad_perm [2,3,0,1]
  x = dpp_add<0x141>(x);   // row_half_mirror
  x = dpp_add<0x140>(x);   // row_mirror
  return x;
}

// Two interleaved row-of-16 reductions; s_nop 1 covers the entry
// VALU-write -> DPP-read hazard (R8 lesson).
__device__ __forceinline__ void duo_reduce(float& a, float& b) {
  float t0, t1;
  asm volatile(
    "s_nop 1\n\t"
    "v_mov_b32_dpp %2, %0 quad_perm:[1,0,3,2] row_mask:0xf bank_mask:0xf\n\t"
    "v_mov_b32_dpp %3, %1 quad_perm:[1,0,3,2] row_mask:0xf bank_mask:0xf\n\t"
    "s_nop 0\n\t"
    "v_add_f32 %0, %0, %2\n\t"
    "v_add_f32 %1, %1, %3\n\t"
    "s_nop 0\n\t"
    "v_mov_b32_dpp %2, %0 quad_perm:[2,3,0,1] row_mask:0xf bank_mask:0xf\n\t"
    "v_mov_b32_dpp %3, %1 quad_perm:[2,3,0,1] row_mask:0xf bank_mask:0xf\n\t"
    "s_nop 0\n\t"
    "v_add_f32 %0, %0, %2\n\t"
    "v_add_f32 %1, %1, %3\n\t"
    "s_nop 0\n\t"
    "v_mov_b32_dpp %2, %0 row_half_mirror row_mask:0xf bank_mask:0xf\n\t"
    "v_mov_b32_dpp %3, %1 row_half_mirror row_mask:0xf bank_mask:0xf\n\t"
    "s_nop 0\n\t"
    "v_add_f32 %0, %0, %2\n\t"
    "v_add_f32 %1, %1, %3\n\t"
    "s_nop 0\n\t"
    "v_mov_b32_dpp %2, %0 row_mirror row_mask:0xf bank_mask:0xf\n\t"
    "v_mov_b32_dpp %3, %1 row_mirror row_mask:0xf bank_mask:0xf\n\t"
    "s_nop 0\n\t"
    "v_add_f32 %0, %0, %2\n\t"
    "v_add_f32 %1, %1, %3"
    : "+v"(a), "+v"(b), "=&v"(t0), "=&v"(t1));
}

__device__ __forceinline__ float dot4(const f32x4& x, const f32x4& y) {
  return fmaf(x[3], y[3], fmaf(x[2], y[2], fmaf(x[1], y[1], x[0] * y[0])));
}

__device__ __forceinline__ void gload_lds16(const float* g, const float* l) {
  __builtin_amdgcn_global_load_lds((const AS1 unsigned*)g, (AS3 unsigned*)l, 16, 0, 0);
}

__global__ __launch_bounds__(64, 1)
void wkv7_scan(const float* __restrict__ R, const float* __restrict__ EW,
               const float* __restrict__ K, const float* __restrict__ V,
               const float* __restrict__ A, const float* __restrict__ B,
               const float* __restrict__ S0, float* __restrict__ X,
               float* __restrict__ SOUT)
{
  // 8 slots x 512 floats (2KB: R|EW|K|A | B|V|pad) = 16 KB
  __shared__ float smem[4096];

  const int blk = blockIdx.x;          // 0..1023
  const int xcd = blk & 7;
  const int m   = blk >> 3;            // 0..127
  const int h   = xcd * 8 + (m & 7);   // head 0..63
  const int br  = m >> 3;              // row block 0..15

  const int lane = threadIdx.x;        // 0..63
  const int cg   = lane & 15;          // cols [cg*4, cg*4+4)
  const int rl   = lane >> 4;          // local row 0..3
  const int row  = br * 4 + rl;        // 0..63
  const int c0   = cg * 4;

  // Staging sources (width-16 lane grouping, R14):
  const int g1   = lane >> 4;          // source-array group 0..3
  const int sub16 = lane & 15;         // 16B chunk within the 256B array
  const float* base1 = (g1 == 0) ? R : (g1 == 1) ? EW : (g1 == 2) ? K : A;
  const float* base2 = (g1 == 0) ? B : V;   // g1>=1 dups V into pad
  const float* p1 = base1 + h * DD + sub16 * 4;
  const float* p2 = base2 + h * DD + sub16 * 4;

  const unsigned lb  = (unsigned)(uintptr_t)(AS3 float*)&smem[0];
  const unsigned vab = lb + (unsigned)(cg * 16);   // vector-read base
  const unsigned vvb = lb + (unsigned)(row * 4);   // v-read base (+1280 imm)

  // y batched store: lane cg<8 stores step (t0+cg) of its row.
  const int ybo = (cg * HD + h * DD + row) * 4;

  f32x4 s;
  {
    const f32x4* sp = (const f32x4*)(S0 + (size_t)h * DD * DD + row * DD + c0);
    s = *sp;
  }

  auto stage = [&](int tt, int slot) {
    const size_t o = (size_t)tt * HD;
    const float* l = &smem[slot * 512];
    gload_lds16(p1 + o, l);          // R|EW|K|A -> slot[0..1024)B
    gload_lds16(p2 + o, l + 256);    // B|V|pad  -> slot[1024..2048)B
  };

  auto lds_read = [&](Buf& d, int slot) {
    unsigned va = vab + (unsigned)(slot * 2048);
    unsigned vv = vvb + (unsigned)(slot * 2048);
    asm volatile(
      "ds_read_b128 %0, %6\n\t"
      "ds_read_b128 %1, %6 offset:256\n\t"
      "ds_read_b128 %2, %6 offset:512\n\t"
      "ds_read_b128 %3, %6 offset:768\n\t"
      "ds_read_b128 %4, %6 offset:1024\n\t"
      "ds_read_b32  %5, %7 offset:1280"
      : "=&v"(d.r), "=&v"(d.e), "=&v"(d.k), "=&v"(d.a), "=&v"(d.b), "=&v"(d.vv)
      : "v"(va), "v"(vv) : "memory");
  };

  auto wait_nx1 = [&](Buf& d) {
    asm volatile("s_waitcnt lgkmcnt(6)"
                 : "+v"(d.r), "+v"(d.e), "+v"(d.k), "+v"(d.a), "+v"(d.b),
                   "+v"(d.vv));
  };

  float sa;              // sa_t = S_{t-1}.a_t, ready at body t entry
  float ybatch = 0.0f;   // reduced y's; lane cg holds step (8m+cg)

  auto body = [&](Buf& cur, Buf& nx1, Buf& nx2, int t) {
    // stage(t+2) (issued at body t-6) resident: bodies t-5..t-1 issued
    // 10 loads + <=1 flush store newer -> vmcnt(10).
    asm volatile("s_waitcnt vmcnt(10)" ::: "memory");
    lds_read(nx2, (t + 2) & 7);
    wait_nx1(nx1);

    // ---- state update for step t (sa ready since last body) ----
    const float vv = cur.vv;
    s[0] = fmaf(cur.e[0], s[0], fmaf(sa, cur.b[0], vv * cur.k[0]));
    s[1] = fmaf(cur.e[1], s[1], fmaf(sa, cur.b[1], vv * cur.k[1]));
    s[2] = fmaf(cur.e[2], s[2], fmaf(sa, cur.b[2], vv * cur.k[2]));
    s[3] = fmaf(cur.e[3], s[3], fmaf(sa, cur.b[3], vv * cur.k[3]));

    // ---- both dots (partials) ----
    float qd = dot4(s, nx1.a);   // -> sa_{t+1}
    float yd = dot4(s, cur.r);   // -> y_t

    stage((t + 8) & (T_LEN - 1), t & 7);

    // ---- interleaved dual reduction ----
    duo_reduce(qd, yd);
    sa = qd;

    // ---- y batching: lane (t&7) keeps y_t; flush every 8 bodies ----
    ybatch = (cg == (t & 7)) ? yd : ybatch;
    if ((t & 7) == 7) {          // compile-time after unroll-8
      if (cg < 8) {              // 32 lanes: 8 t-slots x 4 rows
        int voff = (t - 7) * (HD * 4) + ybo;
        asm volatile("global_store_dword %0, %1, %2"
                     :: "v"(voff), "v"(ybatch), "s"(X) : "memory");
      }
    }
  };

  // Prologue: fill ring (issue order = count order).
  for (int i = 0; i < 8; ++i) {
    stage(i, i);
    __builtin_amdgcn_sched_barrier(0);
  }
  // Slots 0,1 done: stages 2..7 = 12 newer load ops.
  asm volatile("s_waitcnt vmcnt(12)" ::: "memory");

  Buf B0, B1, B2, B3;
  lds_read(B0, 0);
  lds_read(B1, 1);
  asm volatile("s_waitcnt lgkmcnt(0)"
               : "+v"(B0.r), "+v"(B0.e), "+v"(B0.k), "+v"(B0.a), "+v"(B0.b),
                 "+v"(B0.vv), "+v"(B1.a));

  // sa_0 = S_init . a_0 (prologue pays one serial reduce)
  sa = row16_reduce(dot4(s, B0.a));

  for (int t = 0; t < T_LEN; t += 8) {
    body(B0, B1, B2, t);
    body(B1, B2, B3, t + 1);
    body(B2, B3, B0, t + 2);
    body(B3, B0, B1, t + 3);
    body(B0, B1, B2, t + 4);
    body(B1, B2, B3, t + 5);
    body(B2, B3, B0, t + 6);
    body(B3, B0, B1, t + 7);
  }
  // Loop ends at t=2047 with (t&7)==7 -> final flush covered steps 2040..2047.

  *(f32x4*)(SOUT + (size_t)h * DD * DD + row * DD + c0) = s;
}

extern "C" void kernel_launch(void* const* d_in, const int* in_sizes, int n_in,
                              void* d_out, int out_size, void* d_ws, size_t ws_size,
                              hipStream_t stream) {
  // setup_inputs order: seq_length, r, w, k, v, a, b, state2
  const float* r  = (const float*)d_in[1];
  const float* w  = (const float*)d_in[2];
  const float* k  = (const float*)d_in[3];
  const float* v  = (const float*)d_in[4];
  const float* a  = (const float*)d_in[5];
  const float* b  = (const float*)d_in[6];
  const float* s0 = (const float*)d_in[7];

  float* x    = (float*)d_out;                     // (T, H, 1, D)
  float* sout = x + (size_t)T_LEN * HD;            // (H, D, D)

  float* ew = (float*)d_ws;
  (void)ws_size; (void)in_sizes; (void)n_in;

  int n4 = T_LEN * HD / 4;
  hipLaunchKernelGGL(exp_kernel, dim3(1024), dim3(256), 0, stream,
                     (const float4*)w, (float4*)ew, n4);
  hipLaunchKernelGGL(wkv7_scan, dim3(1024), dim3(64), 0, stream,
                     r, ew, k, v, a, b, s0, x, sout);
}